// Round 1
// baseline (1409.524 us; speedup 1.0000x reference)
//
#include <hip/hip_runtime.h>

typedef unsigned short u16;
typedef unsigned int   u32;
typedef __attribute__((ext_vector_type(8))) __bf16 bf16x8;
typedef __attribute__((ext_vector_type(4))) float  f32x4;

// ---------- bf16 helpers (raw-bit, RNE) ----------
__device__ __forceinline__ float b2f(u16 h) {
  union { u32 u; float f; } c; c.u = ((u32)h) << 16; return c.f;
}
__device__ __forceinline__ u16 f2b(float f) {
  union { float f; u32 u; } c; c.f = f;
  u32 u = c.u;
  return (u16)((u + 0x7FFFu + ((u >> 16) & 1u)) >> 16);
}
__device__ __forceinline__ float lo16(u32 u) { union { u32 u; float f; } c; c.u = u << 16;        return c.f; }
__device__ __forceinline__ float hi16(u32 u) { union { u32 u; float f; } c; c.u = u & 0xFFFF0000u; return c.f; }

__device__ __forceinline__ void gll16(const void* g, void* l) {
  __builtin_amdgcn_global_load_lds(
      (__attribute__((address_space(1))) void*)(void*)g,
      (__attribute__((address_space(3))) void*)l, 16, 0, 0);
}

// ---------- weight cast + transpose: W[K][N] f32 -> Wt[N][K] bf16 ----------
__global__ __launch_bounds__(256) void castT(const float* __restrict__ W, u16* __restrict__ Wt,
                                             int K, int N) {
  __shared__ float t[32][33];
  const int n0 = blockIdx.x * 32, k0 = blockIdx.y * 32;
  const int tx = threadIdx.x & 31, ty = threadIdx.x >> 5;  // ty: 0..7
#pragma unroll
  for (int s = 0; s < 32; s += 8)
    t[ty + s][tx] = W[(size_t)(k0 + ty + s) * N + n0 + tx];
  __syncthreads();
#pragma unroll
  for (int s = 0; s < 32; s += 8)
    Wt[(size_t)(n0 + ty + s) * K + k0 + tx] = f2b(t[tx][ty + s]);
}

// ---------- LN1 fused with window partition (pad 64->70, 5x5 windows of 14) ----------
// row = win*196 + l, win = b*25 + wh*5 + ww, l = i*14 + j. Rows 19600..19711 and
// image-pad positions (h>=64 or w>=64) write zeros.
__global__ __launch_bounds__(64)
void ln1win_kernel(const float* __restrict__ x, const float* __restrict__ sc,
                   const float* __restrict__ bi, u16* __restrict__ ywin) {
  const int row = blockIdx.x;
  const int lane = threadIdx.x;
  u32* yrow = (u32*)(ywin + (size_t)row * 768);
  const float* xr = nullptr;
  if (row < 19600) {
    int win = row / 196, l = row % 196;
    int b = win / 25, wh = (win / 5) % 5, ww = win % 5;
    int i = l / 14, j = l % 14;
    int h = wh * 14 + i, w = ww * 14 + j;
    if (h < 64 && w < 64) xr = x + ((size_t)((b * 64 + h) * 64 + w)) * 768;
  }
  if (!xr) {
#pragma unroll
    for (int t = 0; t < 6; ++t) yrow[lane + 64 * t] = 0u;
    return;
  }
  float v[12], s1 = 0.f, s2 = 0.f;
  const float4* x4 = (const float4*)xr;
#pragma unroll
  for (int t = 0; t < 3; ++t) {
    float4 f = x4[t * 64 + lane];
    v[t*4+0]=f.x; v[t*4+1]=f.y; v[t*4+2]=f.z; v[t*4+3]=f.w;
    s1 += f.x + f.y + f.z + f.w;
    s2 += f.x*f.x + f.y*f.y + f.z*f.z + f.w*f.w;
  }
#pragma unroll
  for (int off = 32; off > 0; off >>= 1) { s1 += __shfl_xor(s1, off); s2 += __shfl_xor(s2, off); }
  const float mu = s1 * (1.f / 768.f);
  const float var = s2 * (1.f / 768.f) - mu * mu;
  const float rs = rsqrtf(var + 1e-6f);
#pragma unroll
  for (int t = 0; t < 3; ++t) {
    int c = (t * 64 + lane) * 4;
    u32 lo = (u32)f2b((v[t*4+0]-mu)*rs*sc[c+0] + bi[c+0]) | ((u32)f2b((v[t*4+1]-mu)*rs*sc[c+1] + bi[c+1]) << 16);
    u32 hi = (u32)f2b((v[t*4+2]-mu)*rs*sc[c+2] + bi[c+2]) | ((u32)f2b((v[t*4+3]-mu)*rs*sc[c+3] + bi[c+3]) << 16);
    yrow[(t*64+lane)*2]   = lo;
    yrow[(t*64+lane)*2+1] = hi;
  }
}

// ---------- plain LN (rows of 768) for norm2; input f32 (x2 in d_out), output bf16 ----------
__global__ __launch_bounds__(64)
void ln2_kernel(const float* __restrict__ xin, const float* __restrict__ sc,
                const float* __restrict__ bi, u16* __restrict__ out) {
  const int row = blockIdx.x;
  const int lane = threadIdx.x;
  const float* xr = xin + (size_t)row * 768;
  u32* yrow = (u32*)(out + (size_t)row * 768);
  float v[12], s1 = 0.f, s2 = 0.f;
  const float4* x4 = (const float4*)xr;
#pragma unroll
  for (int t = 0; t < 3; ++t) {
    float4 f = x4[t * 64 + lane];
    v[t*4+0]=f.x; v[t*4+1]=f.y; v[t*4+2]=f.z; v[t*4+3]=f.w;
    s1 += f.x + f.y + f.z + f.w;
    s2 += f.x*f.x + f.y*f.y + f.z*f.z + f.w*f.w;
  }
#pragma unroll
  for (int off = 32; off > 0; off >>= 1) { s1 += __shfl_xor(s1, off); s2 += __shfl_xor(s2, off); }
  const float mu = s1 * (1.f / 768.f);
  const float var = s2 * (1.f / 768.f) - mu * mu;
  const float rs = rsqrtf(var + 1e-6f);
#pragma unroll
  for (int t = 0; t < 3; ++t) {
    int c = (t * 64 + lane) * 4;
    u32 lo = (u32)f2b((v[t*4+0]-mu)*rs*sc[c+0] + bi[c+0]) | ((u32)f2b((v[t*4+1]-mu)*rs*sc[c+1] + bi[c+1]) << 16);
    u32 hi = (u32)f2b((v[t*4+2]-mu)*rs*sc[c+2] + bi[c+2]) | ((u32)f2b((v[t*4+3]-mu)*rs*sc[c+3] + bi[c+3]) << 16);
    yrow[(t*64+lane)*2]   = lo;
    yrow[(t*64+lane)*2+1] = hi;
  }
}

// ---------- 128x128 bf16 MFMA GEMM, A[Mpad][K] @ Bt[N][K]^T, 4 epilogues ----------
// EPI 0: QKV scatter -> qkvout[3][1200][196][64] (+qkv_b), rows<19600
// EPI 1: proj: d_out[b,h,w,c] = resid + acc + bias (window unpartition + crop)
// EPI 2: fc1:  outh = bf16(gelu_exact(acc + bias))
// EPI 3: fc2:  outf[idx] += acc + bias (in-place residual)
template<int EPI>
__global__ __launch_bounds__(256)
void gemm128(const u16* __restrict__ A, const u16* __restrict__ Bt,
             const float* __restrict__ bias, float* __restrict__ outf,
             u16* __restrict__ outh, const float* __restrict__ resid,
             u16* __restrict__ qkvout, int K) {
  __shared__ u16 As[128 * 32];
  __shared__ u16 Bs[128 * 32];
  const int tid = threadIdx.x;
  const int lane = tid & 63, wid = tid >> 6;
  const int wr = wid >> 1, wc = wid & 1;
  const int m0 = blockIdx.y * 128, n0 = blockIdx.x * 128;

  f32x4 acc[4][4] = {};

  // staging: 512 16B-chunks per tile; wave w covers chunks [w*64,w*64+64) and +256
  const int c1 = wid * 64 + lane;
  const int row1 = c1 >> 2, kp1 = (c1 & 3) * 8;
  const int c2 = c1 + 256;
  const int row2 = c2 >> 2, kp2 = (c2 & 3) * 8;
  const u16* a1 = A + (size_t)(m0 + row1) * K + kp1;
  const u16* a2 = A + (size_t)(m0 + row2) * K + kp2;
  const u16* b1 = Bt + (size_t)(n0 + row1) * K + kp1;
  const u16* b2 = Bt + (size_t)(n0 + row2) * K + kp2;
  u16* lA0 = As + wid * 512;  u16* lA1 = As + wid * 512 + 2048;
  u16* lB0 = Bs + wid * 512;  u16* lB1 = Bs + wid * 512 + 2048;

  const int ar = lane & 15, kk = (lane >> 4) * 8;

  for (int kt = 0; kt < K; kt += 32) {
    __syncthreads();
    gll16(a1 + kt, lA0);
    gll16(a2 + kt, lA1);
    gll16(b1 + kt, lB0);
    gll16(b2 + kt, lB1);
    __syncthreads();  // drains vmcnt (compiler emits full waitcnt before s_barrier)
    bf16x8 af[4], bfv[4];
#pragma unroll
    for (int i = 0; i < 4; ++i) {
      af[i]  = *(const bf16x8*)(As + (wr * 64 + i * 16 + ar) * 32 + kk);
      bfv[i] = *(const bf16x8*)(Bs + (wc * 64 + i * 16 + ar) * 32 + kk);
    }
#pragma unroll
    for (int i = 0; i < 4; ++i)
#pragma unroll
      for (int j = 0; j < 4; ++j)
        acc[i][j] = __builtin_amdgcn_mfma_f32_16x16x32_bf16(af[i], bfv[j], acc[i][j], 0, 0, 0);
  }

  // epilogue: C frag mapping col = lane&15, row = (lane>>4)*4 + r  [m89-verified]
  const int rbase = m0 + wr * 64 + (lane >> 4) * 4;
  const int cbase = n0 + wc * 64 + (lane & 15);
#pragma unroll
  for (int i = 0; i < 4; ++i) {
#pragma unroll
    for (int j = 0; j < 4; ++j) {
      const int col = cbase + j * 16;
#pragma unroll
      for (int r = 0; r < 4; ++r) {
        const int row = rbase + i * 16 + r;
        float v = acc[i][j][r];
        if constexpr (EPI == 0) {
          if (row < 19600) {
            v += bias[col];
            int s = col / 768, rem = col % 768;
            int head = rem >> 6, d = rem & 63;
            int win = row / 196, l = row % 196;
            qkvout[(size_t)s * 15052800 + ((size_t)(win * 12 + head) * 196 + l) * 64 + d] = f2b(v);
          }
        } else if constexpr (EPI == 1) {
          if (row < 19600) {
            int win = row / 196, l = row % 196;
            int b = win / 25, wh = (win / 5) % 5, ww = win % 5;
            int i2 = l / 14, j2 = l % 14;
            int h = wh * 14 + i2, w = ww * 14 + j2;
            if (h < 64 && w < 64) {
              size_t idx = ((size_t)((b * 64 + h) * 64 + w)) * 768 + col;
              outf[idx] = resid[idx] + v + bias[col];
            }
          }
        } else if constexpr (EPI == 2) {
          float t = v + bias[col];
          float g = 0.5f * t * (1.0f + erff(t * 0.70710678118f));
          outh[(size_t)row * 3072 + col] = f2b(g);
        } else {
          size_t idx = (size_t)row * 768 + col;
          outf[idx] = outf[idx] + v + bias[col];
        }
      }
    }
  }
}

// ---------- attention: one block per (window, head); VALU compute, LDS-resident ----------
__global__ __launch_bounds__(512)
void attn_kernel(const u16* __restrict__ qkv, const float* __restrict__ relh,
                 const float* __restrict__ relw, u16* __restrict__ obuf) {
  __shared__ u16 Qs[12544];
  __shared__ u16 Ks[12544];
  __shared__ u16 Ps[38416];
  __shared__ alignas(16) float Um[6272];  // BH/BW (f32) then V (bf16), time-shared

  const int tid = threadIdx.x;
  const int wh = blockIdx.x;           // 0..1199
  const int win = wh / 12, head = wh % 12;
  const size_t base = (size_t)wh * 12544;
  const u16* qg = qkv + base;
  const u16* kg = qkv + 15052800 + base;
  const u16* vg = qkv + 30105600 + base;

  {  // stage Q, K (16B chunks)
    const uint4* q4 = (const uint4*)qg;
    const uint4* k4 = (const uint4*)kg;
    uint4* Q4 = (uint4*)Qs; uint4* K4 = (uint4*)Ks;
    for (int c = tid; c < 1568; c += 512) { Q4[c] = q4[c]; K4[c] = k4[c]; }
  }
  __syncthreads();

  // rel-pos bias: BH[r][ki] = q[r] . rel_h[i-ki+13],  BW[r][kj] = q[r] . rel_w[j-kj+13]
  float* BH = Um;
  float* BW = Um + 2744;
  for (int f = tid; f < 5488; f += 512) {
    int r = f / 28, t = f % 28;
    int ki = t % 14, which = t / 14;
    int i = r / 14, j = r % 14;
    int rel = (which ? (j - ki) : (i - ki)) + 13;
    const float* rp = (which ? relw : relh) + rel * 64;
    const uint4* qrow = (const uint4*)(Qs + r * 64);
    float s = 0.f;
#pragma unroll
    for (int c = 0; c < 8; ++c) {
      uint4 u = qrow[c];
      const float4* r4 = (const float4*)(rp + c * 8);
      float4 f0 = r4[0], f1 = r4[1];
      s += lo16(u.x)*f0.x + hi16(u.x)*f0.y + lo16(u.y)*f0.z + hi16(u.y)*f0.w
         + lo16(u.z)*f1.x + hi16(u.z)*f1.y + lo16(u.w)*f1.z + hi16(u.w)*f1.w;
    }
    (which ? BW : BH)[r * 14 + ki] = s;
  }
  __syncthreads();

  // S = 0.125*q.k + BH + BW -> Ps (bf16); per item: 1 q-row (regs) x 49 keys
  for (int it = tid; it < 784; it += 512) {
    int r = it >> 2, kb = (it & 3) * 49;
    float qf[64];
    const uint4* qrow = (const uint4*)(Qs + r * 64);
#pragma unroll
    for (int c = 0; c < 8; ++c) {
      uint4 u = qrow[c];
      qf[c*8+0]=lo16(u.x); qf[c*8+1]=hi16(u.x); qf[c*8+2]=lo16(u.y); qf[c*8+3]=hi16(u.y);
      qf[c*8+4]=lo16(u.z); qf[c*8+5]=hi16(u.z); qf[c*8+6]=lo16(u.w); qf[c*8+7]=hi16(u.w);
    }
    const float* bhr = BH + r * 14;
    const float* bwr = BW + r * 14;
    for (int k = kb; k < kb + 49; ++k) {
      const uint4* krow = (const uint4*)(Ks + k * 64);
      float s = 0.f;
#pragma unroll
      for (int c = 0; c < 8; ++c) {
        uint4 u = krow[c];
        s += qf[c*8+0]*lo16(u.x) + qf[c*8+1]*hi16(u.x) + qf[c*8+2]*lo16(u.y) + qf[c*8+3]*hi16(u.y)
           + qf[c*8+4]*lo16(u.z) + qf[c*8+5]*hi16(u.z) + qf[c*8+6]*lo16(u.w) + qf[c*8+7]*hi16(u.w);
      }
      int ki = k / 14, kj = k - ki * 14;
      Ps[r * 196 + k] = f2b(0.125f * s + bhr[ki] + bwr[kj]);
    }
  }
  __syncthreads();

  // stage V (overwrites BH/BW) + row softmax on Ps
  {
    uint4* V4 = (uint4*)Um;
    const uint4* v4 = (const uint4*)vg;
    for (int c = tid; c < 1568; c += 512) V4[c] = v4[c];
  }
  if (tid < 196) {
    u16* pr = Ps + tid * 196;
    float mx = -1e30f;
    for (int k = 0; k < 196; ++k) mx = fmaxf(mx, b2f(pr[k]));
    float sum = 0.f;
    for (int k = 0; k < 196; ++k) {
      float p = __expf(b2f(pr[k]) - mx);
      sum += p;
      pr[k] = f2b(p);
    }
    float inv = 1.f / sum;
    for (int k = 0; k < 196; ++k) pr[k] = f2b(b2f(pr[k]) * inv);
  }
  __syncthreads();

  // O = P @ V ; item = 2 q-rows x 16 d-cols
  const u16* Vs = (const u16*)Um;
  for (int it = tid; it < 392; it += 512) {
    int rg = it >> 2, db = (it & 3) * 16;
    int r0 = rg * 2;
    const u16* p0 = Ps + r0 * 196;
    const u16* p1 = p0 + 196;
    float a0[16] = {}, a1[16] = {};
    for (int k = 0; k < 196; ++k) {
      float pv0 = b2f(p0[k]), pv1 = b2f(p1[k]);
      const uint4* vr = (const uint4*)(Vs + k * 64 + db);
      uint4 u = vr[0], w = vr[1];
      float vv[16] = { lo16(u.x),hi16(u.x),lo16(u.y),hi16(u.y),lo16(u.z),hi16(u.z),lo16(u.w),hi16(u.w),
                       lo16(w.x),hi16(w.x),lo16(w.y),hi16(w.y),lo16(w.z),hi16(w.z),lo16(w.w),hi16(w.w) };
#pragma unroll
      for (int d = 0; d < 16; ++d) { a0[d] += pv0 * vv[d]; a1[d] += pv1 * vv[d]; }
    }
    u16* o0 = obuf + (size_t)(win * 196 + r0) * 768 + head * 64 + db;
    u16* o1 = o0 + 768;
    u32 w0[8], w1[8];
#pragma unroll
    for (int d = 0; d < 8; ++d) {
      w0[d] = (u32)f2b(a0[2*d]) | ((u32)f2b(a0[2*d+1]) << 16);
      w1[d] = (u32)f2b(a1[2*d]) | ((u32)f2b(a1[2*d+1]) << 16);
    }
    ((uint4*)o0)[0] = make_uint4(w0[0], w0[1], w0[2], w0[3]);
    ((uint4*)o0)[1] = make_uint4(w0[4], w0[5], w0[6], w0[7]);
    ((uint4*)o1)[0] = make_uint4(w1[0], w1[1], w1[2], w1[3]);
    ((uint4*)o1)[1] = make_uint4(w1[4], w1[5], w1[6], w1[7]);
  }
}

extern "C" void kernel_launch(void* const* d_in, const int* in_sizes, int n_in,
                              void* d_out, int out_size, void* d_ws, size_t ws_size,
                              hipStream_t stream) {
  const float* x      = (const float*)d_in[0];
  const float* n1s    = (const float*)d_in[1];
  const float* n1b    = (const float*)d_in[2];
  const float* qkv_w  = (const float*)d_in[3];
  const float* qkv_b  = (const float*)d_in[4];
  const float* rel_h  = (const float*)d_in[5];
  const float* rel_w  = (const float*)d_in[6];
  const float* proj_w = (const float*)d_in[7];
  const float* proj_b = (const float*)d_in[8];
  const float* n2s    = (const float*)d_in[9];
  const float* n2b    = (const float*)d_in[10];
  const float* fc1_w  = (const float*)d_in[11];
  const float* fc1_b  = (const float*)d_in[12];
  const float* fc2_w  = (const float*)d_in[13];
  const float* fc2_b  = (const float*)d_in[14];
  float* out = (float*)d_out;

  // workspace layout (bytes); peak need ~140 MB
  char* ws = (char*)d_ws;
  u16* qkv_wt = (u16*)(ws + 0);            // [2304][768]
  u16* proj_wt = (u16*)(ws + 3538944);     // [768][768]
  u16* fc1_wt = (u16*)(ws + 4718592);      // [3072][768]
  u16* fc2_wt = (u16*)(ws + 9437184);      // [768][3072]
  u16* ywin   = (u16*)(ws + 14155776);     // [19712][768]; later obuf; later m1 head
  u16* qkvbuf = (u16*)(ws + 44433408);     // [3][1200][196][64]
  u16* m1     = ywin;                      // [16384][3072] spans ywin+qkvbuf
  u16* h2     = (u16*)(ws + 114819072);    // [16384][768] (after m1 end)
  if (ws_size < 139984896) return;         // diagnosable: leaves d_out poisoned

  castT<<<dim3(72, 24), 256, 0, stream>>>(qkv_w, qkv_wt, 768, 2304);
  castT<<<dim3(24, 24), 256, 0, stream>>>(proj_w, proj_wt, 768, 768);
  castT<<<dim3(96, 24), 256, 0, stream>>>(fc1_w, fc1_wt, 768, 3072);
  castT<<<dim3(24, 96), 256, 0, stream>>>(fc2_w, fc2_wt, 3072, 768);

  ln1win_kernel<<<19712, 64, 0, stream>>>(x, n1s, n1b, ywin);

  gemm128<0><<<dim3(18, 154), 256, 0, stream>>>(ywin, qkv_wt, qkv_b, nullptr, nullptr, nullptr, qkvbuf, 768);

  attn_kernel<<<1200, 512, 0, stream>>>(qkvbuf, rel_h, rel_w, ywin /* obuf */);

  gemm128<1><<<dim3(6, 154), 256, 0, stream>>>(ywin, proj_wt, proj_b, out, nullptr, x, nullptr, 768);

  ln2_kernel<<<16384, 64, 0, stream>>>(out, n2s, n2b, h2);

  gemm128<2><<<dim3(24, 128), 256, 0, stream>>>(h2, fc1_wt, fc1_b, nullptr, m1, nullptr, nullptr, 768);

  gemm128<3><<<dim3(6, 128), 256, 0, stream>>>(m1, fc2_wt, fc2_b, out, nullptr, nullptr, nullptr, 3072);
}

// Round 3
// 1041.485 us; speedup vs baseline: 1.3534x; 1.3534x over previous
//
#include <hip/hip_runtime.h>

typedef unsigned short u16;
typedef unsigned int   u32;
typedef __attribute__((ext_vector_type(8))) __bf16 bf16x8;
typedef __attribute__((ext_vector_type(4))) float  f32x4;

// ---------- bf16 helpers (raw-bit, RNE) ----------
__device__ __forceinline__ float b2f(u16 h) {
  union { u32 u; float f; } c; c.u = ((u32)h) << 16; return c.f;
}
__device__ __forceinline__ u16 f2b(float f) {
  union { float f; u32 u; } c; c.f = f;
  u32 u = c.u;
  return (u16)((u + 0x7FFFu + ((u >> 16) & 1u)) >> 16);
}
__device__ __forceinline__ float lo16(u32 u) { union { u32 u; float f; } c; c.u = u << 16;        return c.f; }
__device__ __forceinline__ float hi16(u32 u) { union { u32 u; float f; } c; c.u = u & 0xFFFF0000u; return c.f; }

__device__ __forceinline__ bf16x8 bzero() {
  union { int4 i; bf16x8 v; } u; u.i = make_int4(0, 0, 0, 0); return u.v;
}

__device__ __forceinline__ void gll16(const void* g, void* l) {
  __builtin_amdgcn_global_load_lds(
      (__attribute__((address_space(1))) void*)(void*)g,
      (__attribute__((address_space(3))) void*)l, 16, 0, 0);
}

// ---------- weight cast + transpose: W[K][N] f32 -> Wt[N][K] bf16 ----------
__global__ __launch_bounds__(256) void castT(const float* __restrict__ W, u16* __restrict__ Wt,
                                             int K, int N) {
  __shared__ float t[32][33];
  const int n0 = blockIdx.x * 32, k0 = blockIdx.y * 32;
  const int tx = threadIdx.x & 31, ty = threadIdx.x >> 5;  // ty: 0..7
#pragma unroll
  for (int s = 0; s < 32; s += 8)
    t[ty + s][tx] = W[(size_t)(k0 + ty + s) * N + n0 + tx];
  __syncthreads();
#pragma unroll
  for (int s = 0; s < 32; s += 8)
    Wt[(size_t)(n0 + ty + s) * K + k0 + tx] = f2b(t[tx][ty + s]);
}

// ---------- LN1 fused with window partition (pad 64->70, 5x5 windows of 14) ----------
__global__ __launch_bounds__(64)
void ln1win_kernel(const float* __restrict__ x, const float* __restrict__ sc,
                   const float* __restrict__ bi, u16* __restrict__ ywin) {
  const int row = blockIdx.x;
  const int lane = threadIdx.x;
  u32* yrow = (u32*)(ywin + (size_t)row * 768);
  const float* xr = nullptr;
  if (row < 19600) {
    int win = row / 196, l = row % 196;
    int b = win / 25, wh = (win / 5) % 5, ww = win % 5;
    int i = l / 14, j = l % 14;
    int h = wh * 14 + i, w = ww * 14 + j;
    if (h < 64 && w < 64) xr = x + ((size_t)((b * 64 + h) * 64 + w)) * 768;
  }
  if (!xr) {
#pragma unroll
    for (int t = 0; t < 6; ++t) yrow[lane + 64 * t] = 0u;
    return;
  }
  float v[12], s1 = 0.f, s2 = 0.f;
  const float4* x4 = (const float4*)xr;
#pragma unroll
  for (int t = 0; t < 3; ++t) {
    float4 f = x4[t * 64 + lane];
    v[t*4+0]=f.x; v[t*4+1]=f.y; v[t*4+2]=f.z; v[t*4+3]=f.w;
    s1 += f.x + f.y + f.z + f.w;
    s2 += f.x*f.x + f.y*f.y + f.z*f.z + f.w*f.w;
  }
#pragma unroll
  for (int off = 32; off > 0; off >>= 1) { s1 += __shfl_xor(s1, off); s2 += __shfl_xor(s2, off); }
  const float mu = s1 * (1.f / 768.f);
  const float var = s2 * (1.f / 768.f) - mu * mu;
  const float rs = rsqrtf(var + 1e-6f);
#pragma unroll
  for (int t = 0; t < 3; ++t) {
    int c = (t * 64 + lane) * 4;
    u32 lo = (u32)f2b((v[t*4+0]-mu)*rs*sc[c+0] + bi[c+0]) | ((u32)f2b((v[t*4+1]-mu)*rs*sc[c+1] + bi[c+1]) << 16);
    u32 hi = (u32)f2b((v[t*4+2]-mu)*rs*sc[c+2] + bi[c+2]) | ((u32)f2b((v[t*4+3]-mu)*rs*sc[c+3] + bi[c+3]) << 16);
    yrow[(t*64+lane)*2]   = lo;
    yrow[(t*64+lane)*2+1] = hi;
  }
}

// ---------- plain LN (rows of 768) for norm2 ----------
__global__ __launch_bounds__(64)
void ln2_kernel(const float* __restrict__ xin, const float* __restrict__ sc,
                const float* __restrict__ bi, u16* __restrict__ out) {
  const int row = blockIdx.x;
  const int lane = threadIdx.x;
  const float* xr = xin + (size_t)row * 768;
  u32* yrow = (u32*)(out + (size_t)row * 768);
  float v[12], s1 = 0.f, s2 = 0.f;
  const float4* x4 = (const float4*)xr;
#pragma unroll
  for (int t = 0; t < 3; ++t) {
    float4 f = x4[t * 64 + lane];
    v[t*4+0]=f.x; v[t*4+1]=f.y; v[t*4+2]=f.z; v[t*4+3]=f.w;
    s1 += f.x + f.y + f.z + f.w;
    s2 += f.x*f.x + f.y*f.y + f.z*f.z + f.w*f.w;
  }
#pragma unroll
  for (int off = 32; off > 0; off >>= 1) { s1 += __shfl_xor(s1, off); s2 += __shfl_xor(s2, off); }
  const float mu = s1 * (1.f / 768.f);
  const float var = s2 * (1.f / 768.f) - mu * mu;
  const float rs = rsqrtf(var + 1e-6f);
#pragma unroll
  for (int t = 0; t < 3; ++t) {
    int c = (t * 64 + lane) * 4;
    u32 lo = (u32)f2b((v[t*4+0]-mu)*rs*sc[c+0] + bi[c+0]) | ((u32)f2b((v[t*4+1]-mu)*rs*sc[c+1] + bi[c+1]) << 16);
    u32 hi = (u32)f2b((v[t*4+2]-mu)*rs*sc[c+2] + bi[c+2]) | ((u32)f2b((v[t*4+3]-mu)*rs*sc[c+3] + bi[c+3]) << 16);
    yrow[(t*64+lane)*2]   = lo;
    yrow[(t*64+lane)*2+1] = hi;
  }
}

// ---------- 128x128 bf16 MFMA GEMM, A[Mpad][K] @ Bt[N][K]^T, 4 epilogues ----------
template<int EPI>
__global__ __launch_bounds__(256)
void gemm128(const u16* __restrict__ A, const u16* __restrict__ Bt,
             const float* __restrict__ bias, float* __restrict__ outf,
             u16* __restrict__ outh, const float* __restrict__ resid,
             u16* __restrict__ qkvout, int K) {
  __shared__ u16 As[128 * 32];
  __shared__ u16 Bs[128 * 32];
  const int tid = threadIdx.x;
  const int lane = tid & 63, wid = tid >> 6;
  const int wr = wid >> 1, wc = wid & 1;
  const int m0 = blockIdx.y * 128, n0 = blockIdx.x * 128;

  f32x4 acc[4][4] = {};

  const int c1 = wid * 64 + lane;
  const int row1 = c1 >> 2, kp1 = (c1 & 3) * 8;
  const int c2 = c1 + 256;
  const int row2 = c2 >> 2, kp2 = (c2 & 3) * 8;
  const u16* a1 = A + (size_t)(m0 + row1) * K + kp1;
  const u16* a2 = A + (size_t)(m0 + row2) * K + kp2;
  const u16* b1 = Bt + (size_t)(n0 + row1) * K + kp1;
  const u16* b2 = Bt + (size_t)(n0 + row2) * K + kp2;
  u16* lA0 = As + wid * 512;  u16* lA1 = As + wid * 512 + 2048;
  u16* lB0 = Bs + wid * 512;  u16* lB1 = Bs + wid * 512 + 2048;

  const int ar = lane & 15, kk = (lane >> 4) * 8;

  for (int kt = 0; kt < K; kt += 32) {
    __syncthreads();
    gll16(a1 + kt, lA0);
    gll16(a2 + kt, lA1);
    gll16(b1 + kt, lB0);
    gll16(b2 + kt, lB1);
    __syncthreads();
    bf16x8 af[4], bfv[4];
#pragma unroll
    for (int i = 0; i < 4; ++i) {
      af[i]  = *(const bf16x8*)(As + (wr * 64 + i * 16 + ar) * 32 + kk);
      bfv[i] = *(const bf16x8*)(Bs + (wc * 64 + i * 16 + ar) * 32 + kk);
    }
#pragma unroll
    for (int i = 0; i < 4; ++i)
#pragma unroll
      for (int j = 0; j < 4; ++j)
        acc[i][j] = __builtin_amdgcn_mfma_f32_16x16x32_bf16(af[i], bfv[j], acc[i][j], 0, 0, 0);
  }

  const int rbase = m0 + wr * 64 + (lane >> 4) * 4;
  const int cbase = n0 + wc * 64 + (lane & 15);
#pragma unroll
  for (int i = 0; i < 4; ++i) {
#pragma unroll
    for (int j = 0; j < 4; ++j) {
      const int col = cbase + j * 16;
#pragma unroll
      for (int r = 0; r < 4; ++r) {
        const int row = rbase + i * 16 + r;
        float v = acc[i][j][r];
        if constexpr (EPI == 0) {
          if (row < 19600) {
            v += bias[col];
            if (col < 768) v *= 0.125f;  // fold softmax scale into Q (pow2: lossless)
            int s = col / 768, rem = col % 768;
            int head = rem >> 6, d = rem & 63;
            int win = row / 196, l = row % 196;
            qkvout[(size_t)s * 15052800 + ((size_t)(win * 12 + head) * 196 + l) * 64 + d] = f2b(v);
          }
        } else if constexpr (EPI == 1) {
          if (row < 19600) {
            int win = row / 196, l = row % 196;
            int b = win / 25, wh = (win / 5) % 5, ww = win % 5;
            int i2 = l / 14, j2 = l % 14;
            int h = wh * 14 + i2, w = ww * 14 + j2;
            if (h < 64 && w < 64) {
              size_t idx = ((size_t)((b * 64 + h) * 64 + w)) * 768 + col;
              outf[idx] = resid[idx] + v + bias[col];
            }
          }
        } else if constexpr (EPI == 2) {
          float t = v + bias[col];
          float g = 0.5f * t * (1.0f + erff(t * 0.70710678118f));
          outh[(size_t)row * 3072 + col] = f2b(g);
        } else {
          size_t idx = (size_t)row * 768 + col;
          outf[idx] = outf[idx] + v + bias[col];
        }
      }
    }
  }
}

// ---------- decomposed rel-pos bias: BH[wh][r][ki] = 8 * qscaled[r].relh[i-ki+13] ----------
__global__ __launch_bounds__(256)
void relbias_kernel(const u16* __restrict__ qkv, const float* __restrict__ relh,
                    const float* __restrict__ relw, u16* __restrict__ BH,
                    u16* __restrict__ BW) {
  __shared__ u16 Qs[196 * 64];
  const int wh = blockIdx.x, tid = threadIdx.x;
  const u16* qg = qkv + (size_t)wh * 12544;
  for (int ch = tid; ch < 1568; ch += 256) ((uint4*)Qs)[ch] = ((const uint4*)qg)[ch];
  __syncthreads();
  for (int f = tid; f < 5488; f += 256) {
    int r = f / 28, t = f - r * 28;
    int isW = (t >= 14) ? 1 : 0;
    int ki = isW ? (t - 14) : t;
    int i = r / 14, j = r - i * 14;
    int rel = (isW ? j : i) - ki + 13;
    const float* rp = (isW ? relw : relh) + rel * 64;
    const uint4* qrow = (const uint4*)(Qs + r * 64);
    float s = 0.f;
#pragma unroll
    for (int cc = 0; cc < 8; ++cc) {
      uint4 u = qrow[cc];
      float4 f0 = ((const float4*)rp)[2 * cc], f1 = ((const float4*)rp)[2 * cc + 1];
      s += lo16(u.x)*f0.x + hi16(u.x)*f0.y + lo16(u.y)*f0.z + hi16(u.y)*f0.w
         + lo16(u.z)*f1.x + hi16(u.z)*f1.y + lo16(u.w)*f1.z + hi16(u.w)*f1.w;
    }
    (isW ? BW : BH)[(size_t)wh * 2744 + r * 14 + ki] = f2b(8.f * s);  // q was pre-scaled 0.125
  }
}

// ---------- MFMA attention: block = (window, head), 4 waves, 80KB LDS ----------
// S tiles 16x16x(k=64), online two-pass softmax in C-frag layout, PV via per-wave P strip.
// All LDS XOR-swizzled: byte = (row*stride + 2k) ^ ((row&7)<<4)  [16B-granule perm]
__global__ __launch_bounds__(256)
void attn_mfma(const u16* __restrict__ qkv, const u16* __restrict__ BHg,
               const u16* __restrict__ BWg, u16* __restrict__ obuf) {
  __shared__ u16 Ks[196 * 64];        // 25,088 B  (B-frag source for S)
  __shared__ u16 Vt[64 * 208];        // 26,624 B  (V^T, cols>=196 zero)
  __shared__ u16 Pst[4][16 * 208];    // 26,624 B  (per-wave P strip)
  __shared__ u16 Bst[4][448];         // 3,584 B   (per-wave BH/BW strip, u32-staged)

  const int tid = threadIdx.x;
  const int lane = tid & 63, w = tid >> 6;
  const int c = lane & 15, g = lane >> 4;
  const int wh = blockIdx.x;
  const int win = wh / 12, head = wh % 12;
  const u16* qg = qkv + (size_t)wh * 12544;
  const u16* kg = qg + 15052800;
  const u16* vg = qg + 30105600;

  // phase 0: zero Vt (pad cols must be 0)
  for (int i = tid; i < 1664; i += 256) ((uint4*)Vt)[i] = make_uint4(0, 0, 0, 0);
  __syncthreads();
  // phase 1: stage K (swizzled 16B chunks) + V transposed (swizzled u16 scatter)
  for (int idx = tid; idx < 1568; idx += 256) {
    int row = idx >> 3, ch = idx & 7;
    uint4 d = *(const uint4*)(kg + row * 64 + ch * 8);
    *(uint4*)((char*)Ks + (((u32)row * 128 + ch * 16) ^ ((row & 7) << 4))) = d;
  }
  for (int idx = tid; idx < 1568; idx += 256) {
    int k = idx >> 3, c0 = (idx & 7) * 8;
    uint4 d = *(const uint4*)(vg + k * 64 + c0);
    u16 e[8];
    e[0] = d.x & 0xFFFF; e[1] = d.x >> 16; e[2] = d.y & 0xFFFF; e[3] = d.y >> 16;
    e[4] = d.z & 0xFFFF; e[5] = d.z >> 16; e[6] = d.w & 0xFFFF; e[7] = d.w >> 16;
#pragma unroll
    for (int j = 0; j < 8; ++j) {
      int col = c0 + j;
      u32 byte = ((u32)col * 416 + 2 * k) ^ ((col & 7) << 4);
      *(u16*)((char*)Vt + byte) = e[j];
    }
  }
  __syncthreads();

  // row-tile loop: wave w owns tiles w, w+4, w+8 (+12 for w==0)
  for (int rt = w; rt < 13; rt += 4) {
    const int rbase = rt * 16;

    // Q A-frags direct from global (guarded)
    bf16x8 qf0 = bzero(), qf1 = bzero();
    {
      int qrow = rbase + c;
      if (qrow < 196) {
        qf0 = *(const bf16x8*)(qg + qrow * 64 + g * 8);
        qf1 = *(const bf16x8*)(qg + qrow * 64 + 32 + g * 8);
      }
    }
    // stage bias strip (16 rows x 14 of BH and BW) as u32s
#pragma unroll
    for (int t = 0; t < 4; ++t) {
      int idx = lane + t * 64;
      if (idx < 224) {
        const u32* src = (const u32*)((idx < 112) ? BHg : BWg);
        int off = (idx < 112) ? idx : idx - 112;
        ((u32*)Bst[w])[idx] = src[(size_t)(wh * 196 + rbase) * 7 + off];
      }
    }

    // ---- S = Qs @ K^T ----
    f32x4 acc[13];
#pragma unroll
    for (int ct = 0; ct < 13; ++ct) acc[ct] = (f32x4){0.f, 0.f, 0.f, 0.f};
#pragma unroll
    for (int ct = 0; ct < 13; ++ct) {
      int kcol = ct * 16 + c;
      bf16x8 kf0 = bzero(), kf1 = bzero();
      if (kcol < 196) {
        u32 b0 = ((u32)kcol * 128 + g * 16) ^ ((kcol & 7) << 4);
        u32 b1 = ((u32)kcol * 128 + 64 + g * 16) ^ ((kcol & 7) << 4);
        kf0 = *(const bf16x8*)((char*)Ks + b0);
        kf1 = *(const bf16x8*)((char*)Ks + b1);
      }
      acc[ct] = __builtin_amdgcn_mfma_f32_16x16x32_bf16(qf0, kf0, acc[ct], 0, 0, 0);
      acc[ct] = __builtin_amdgcn_mfma_f32_16x16x32_bf16(qf1, kf1, acc[ct], 0, 0, 0);
    }

    // ---- bias add + mask + softmax (C-frag layout: row=g*4+r, col=ct*16+c) ----
    float m0[4] = {-3e38f, -3e38f, -3e38f, -3e38f};
#pragma unroll
    for (int ct = 0; ct < 13; ++ct) {
      int k = ct * 16 + c;
      bool valid = k < 196;
      int ki = valid ? (k / 14) : 0;
      int kj = valid ? (k - ki * 14) : 0;
#pragma unroll
      for (int r = 0; r < 4; ++r) {
        int rr = g * 4 + r;
        float v;
        if (valid) v = acc[ct][r] + b2f(Bst[w][rr * 14 + ki]) + b2f(Bst[w][224 + rr * 14 + kj]);
        else v = -3e38f;
        acc[ct][r] = v;
        m0[r] = fmaxf(m0[r], v);
      }
    }
#pragma unroll
    for (int r = 0; r < 4; ++r) {
      m0[r] = fmaxf(m0[r], __shfl_xor(m0[r], 1));
      m0[r] = fmaxf(m0[r], __shfl_xor(m0[r], 2));
      m0[r] = fmaxf(m0[r], __shfl_xor(m0[r], 4));
      m0[r] = fmaxf(m0[r], __shfl_xor(m0[r], 8));
    }
    float sum[4] = {0.f, 0.f, 0.f, 0.f};
#pragma unroll
    for (int ct = 0; ct < 13; ++ct)
#pragma unroll
      for (int r = 0; r < 4; ++r) {
        float p = __expf(acc[ct][r] - m0[r]);
        acc[ct][r] = p;
        sum[r] += p;
      }
#pragma unroll
    for (int r = 0; r < 4; ++r) {
      sum[r] += __shfl_xor(sum[r], 1);
      sum[r] += __shfl_xor(sum[r], 2);
      sum[r] += __shfl_xor(sum[r], 4);
      sum[r] += __shfl_xor(sum[r], 8);
      sum[r] = 1.f / sum[r];
    }
    // write P strip (bf16, swizzled)
#pragma unroll
    for (int ct = 0; ct < 13; ++ct) {
      int k2 = 2 * (ct * 16 + c);
#pragma unroll
      for (int r = 0; r < 4; ++r) {
        int rr = g * 4 + r;
        u32 byte = ((u32)rr * 416 + k2) ^ ((rr & 7) << 4);
        *(u16*)((char*)Pst[w] + byte) = f2b(acc[ct][r] * sum[r]);
      }
    }

    // ---- O = P @ V (A = P strip, B = Vt rows) ----
    f32x4 o[4];
#pragma unroll
    for (int nt = 0; nt < 4; ++nt) o[nt] = (f32x4){0.f, 0.f, 0.f, 0.f};
#pragma unroll
    for (int ks = 0; ks < 7; ++ks) {
      int slice = ks * 32 + g * 8;
      bf16x8 pa = bzero();
      if (slice < 208) {
        u32 byte = ((u32)c * 416 + 2 * slice) ^ ((c & 7) << 4);
        pa = *(const bf16x8*)((char*)Pst[w] + byte);
      }
#pragma unroll
      for (int nt = 0; nt < 4; ++nt) {
        bf16x8 vb = bzero();
        if (slice < 208) {
          int n = nt * 16 + c;
          u32 byte = ((u32)n * 416 + 2 * slice) ^ ((n & 7) << 4);
          vb = *(const bf16x8*)((char*)Vt + byte);
        }
        o[nt] = __builtin_amdgcn_mfma_f32_16x16x32_bf16(pa, vb, o[nt], 0, 0, 0);
      }
    }
    // write O rows (C layout: row=g*4+r -> q, col=nt*16+c -> d)
#pragma unroll
    for (int nt = 0; nt < 4; ++nt) {
#pragma unroll
      for (int r = 0; r < 4; ++r) {
        int q = rbase + g * 4 + r;
        if (q < 196)
          obuf[(size_t)(win * 196 + q) * 768 + head * 64 + nt * 16 + c] = f2b(o[nt][r]);
      }
    }
  }
}

extern "C" void kernel_launch(void* const* d_in, const int* in_sizes, int n_in,
                              void* d_out, int out_size, void* d_ws, size_t ws_size,
                              hipStream_t stream) {
  const float* x      = (const float*)d_in[0];
  const float* n1s    = (const float*)d_in[1];
  const float* n1b    = (const float*)d_in[2];
  const float* qkv_w  = (const float*)d_in[3];
  const float* qkv_b  = (const float*)d_in[4];
  const float* rel_h  = (const float*)d_in[5];
  const float* rel_w  = (const float*)d_in[6];
  const float* proj_w = (const float*)d_in[7];
  const float* proj_b = (const float*)d_in[8];
  const float* n2s    = (const float*)d_in[9];
  const float* n2b    = (const float*)d_in[10];
  const float* fc1_w  = (const float*)d_in[11];
  const float* fc1_b  = (const float*)d_in[12];
  const float* fc2_w  = (const float*)d_in[13];
  const float* fc2_b  = (const float*)d_in[14];
  float* out = (float*)d_out;

  char* ws = (char*)d_ws;
  u16* qkv_wt = (u16*)(ws + 0);            // [2304][768]
  u16* proj_wt = (u16*)(ws + 3538944);     // [768][768]
  u16* fc1_wt = (u16*)(ws + 4718592);      // [3072][768]
  u16* fc2_wt = (u16*)(ws + 9437184);      // [768][3072]
  u16* ywin   = (u16*)(ws + 14155776);     // [19712][768]; later obuf; later m1 head
  u16* qkvbuf = (u16*)(ws + 44433408);     // [3][1200][196][64]
  u16* m1     = ywin;                      // [16384][3072] spans ywin+qkvbuf
  u16* h2     = (u16*)(ws + 114819072);    // [16384][768]
  u16* BH     = (u16*)(ws + 139984896);    // [1200][196][14] bf16
  u16* BW     = (u16*)(ws + 146570496);    // [1200][196][14] bf16
  if (ws_size < 153160192) return;         // diagnosable: leaves d_out poisoned

  castT<<<dim3(72, 24), 256, 0, stream>>>(qkv_w, qkv_wt, 768, 2304);
  castT<<<dim3(24, 24), 256, 0, stream>>>(proj_w, proj_wt, 768, 768);
  castT<<<dim3(96, 24), 256, 0, stream>>>(fc1_w, fc1_wt, 768, 3072);
  castT<<<dim3(24, 96), 256, 0, stream>>>(fc2_w, fc2_wt, 3072, 768);

  ln1win_kernel<<<19712, 64, 0, stream>>>(x, n1s, n1b, ywin);

  gemm128<0><<<dim3(18, 154), 256, 0, stream>>>(ywin, qkv_wt, qkv_b, nullptr, nullptr, nullptr, qkvbuf, 768);

  relbias_kernel<<<1200, 256, 0, stream>>>(qkvbuf, rel_h, rel_w, BH, BW);

  attn_mfma<<<1200, 256, 0, stream>>>(qkvbuf, BH, BW, ywin /* obuf */);

  gemm128<1><<<dim3(6, 154), 256, 0, stream>>>(ywin, proj_wt, proj_b, out, nullptr, x, nullptr, 768);

  ln2_kernel<<<16384, 64, 0, stream>>>(out, n2s, n2b, h2);

  gemm128<2><<<dim3(24, 128), 256, 0, stream>>>(h2, fc1_wt, fc1_b, nullptr, m1, nullptr, nullptr, 768);

  gemm128<3><<<dim3(6, 128), 256, 0, stream>>>(m1, fc2_wt, fc2_b, out, nullptr, nullptr, nullptr, 3072);
}

// Round 6
// 835.661 us; speedup vs baseline: 1.6867x; 1.2463x over previous
//
#include <hip/hip_runtime.h>

typedef unsigned short u16;
typedef unsigned int   u32;
typedef __attribute__((ext_vector_type(8))) __bf16 bf16x8;
typedef __attribute__((ext_vector_type(4))) float  f32x4;

// ---------- bf16 helpers (raw-bit, RNE) ----------
__device__ __forceinline__ float b2f(u16 h) {
  union { u32 u; float f; } c; c.u = ((u32)h) << 16; return c.f;
}
__device__ __forceinline__ u16 f2b(float f) {
  union { float f; u32 u; } c; c.f = f;
  u32 u = c.u;
  return (u16)((u + 0x7FFFu + ((u >> 16) & 1u)) >> 16);
}
__device__ __forceinline__ float lo16(u32 u) { union { u32 u; float f; } c; c.u = u << 16;        return c.f; }
__device__ __forceinline__ float hi16(u32 u) { union { u32 u; float f; } c; c.u = u & 0xFFFF0000u; return c.f; }

__device__ __forceinline__ bf16x8 bzero() {
  union { int4 i; bf16x8 v; } u; u.i = make_int4(0, 0, 0, 0); return u.v;
}

__device__ __forceinline__ void gll16(const void* g, void* l) {
  __builtin_amdgcn_global_load_lds(
      (__attribute__((address_space(1))) void*)(void*)g,
      (__attribute__((address_space(3))) void*)l, 16, 0, 0);
}

// ---------- weight cast + transpose: W[K][N] f32 -> Wt[N][K] bf16 ----------
__global__ __launch_bounds__(256) void castT(const float* __restrict__ W, u16* __restrict__ Wt,
                                             int K, int N) {
  __shared__ float t[32][33];
  const int n0 = blockIdx.x * 32, k0 = blockIdx.y * 32;
  const int tx = threadIdx.x & 31, ty = threadIdx.x >> 5;  // ty: 0..7
#pragma unroll
  for (int s = 0; s < 32; s += 8)
    t[ty + s][tx] = W[(size_t)(k0 + ty + s) * N + n0 + tx];
  __syncthreads();
#pragma unroll
  for (int s = 0; s < 32; s += 8)
    Wt[(size_t)(n0 + ty + s) * K + k0 + tx] = f2b(t[tx][ty + s]);
}

// ---------- LN1 fused with window partition (pad 64->70, 5x5 windows of 14) ----------
__global__ __launch_bounds__(64)
void ln1win_kernel(const float* __restrict__ x, const float* __restrict__ sc,
                   const float* __restrict__ bi, u16* __restrict__ ywin) {
  const int row = blockIdx.x;
  const int lane = threadIdx.x;
  u32* yrow = (u32*)(ywin + (size_t)row * 768);
  const float* xr = nullptr;
  if (row < 19600) {
    int win = row / 196, l = row % 196;
    int b = win / 25, wh = (win / 5) % 5, ww = win % 5;
    int i = l / 14, j = l % 14;
    int h = wh * 14 + i, w = ww * 14 + j;
    if (h < 64 && w < 64) xr = x + ((size_t)((b * 64 + h) * 64 + w)) * 768;
  }
  if (!xr) {
#pragma unroll
    for (int t = 0; t < 6; ++t) yrow[lane + 64 * t] = 0u;
    return;
  }
  float v[12], s1 = 0.f, s2 = 0.f;
  const float4* x4 = (const float4*)xr;
#pragma unroll
  for (int t = 0; t < 3; ++t) {
    float4 f = x4[t * 64 + lane];
    v[t*4+0]=f.x; v[t*4+1]=f.y; v[t*4+2]=f.z; v[t*4+3]=f.w;
    s1 += f.x + f.y + f.z + f.w;
    s2 += f.x*f.x + f.y*f.y + f.z*f.z + f.w*f.w;
  }
#pragma unroll
  for (int off = 32; off > 0; off >>= 1) { s1 += __shfl_xor(s1, off); s2 += __shfl_xor(s2, off); }
  const float mu = s1 * (1.f / 768.f);
  const float var = s2 * (1.f / 768.f) - mu * mu;
  const float rs = rsqrtf(var + 1e-6f);
#pragma unroll
  for (int t = 0; t < 3; ++t) {
    int c = (t * 64 + lane) * 4;
    u32 lo = (u32)f2b((v[t*4+0]-mu)*rs*sc[c+0] + bi[c+0]) | ((u32)f2b((v[t*4+1]-mu)*rs*sc[c+1] + bi[c+1]) << 16);
    u32 hi = (u32)f2b((v[t*4+2]-mu)*rs*sc[c+2] + bi[c+2]) | ((u32)f2b((v[t*4+3]-mu)*rs*sc[c+3] + bi[c+3]) << 16);
    yrow[(t*64+lane)*2]   = lo;
    yrow[(t*64+lane)*2+1] = hi;
  }
}

// ---------- plain LN (rows of 768) for norm2 ----------
__global__ __launch_bounds__(64)
void ln2_kernel(const float* __restrict__ xin, const float* __restrict__ sc,
                const float* __restrict__ bi, u16* __restrict__ out) {
  const int row = blockIdx.x;
  const int lane = threadIdx.x;
  const float* xr = xin + (size_t)row * 768;
  u32* yrow = (u32*)(out + (size_t)row * 768);
  float v[12], s1 = 0.f, s2 = 0.f;
  const float4* x4 = (const float4*)xr;
#pragma unroll
  for (int t = 0; t < 3; ++t) {
    float4 f = x4[t * 64 + lane];
    v[t*4+0]=f.x; v[t*4+1]=f.y; v[t*4+2]=f.z; v[t*4+3]=f.w;
    s1 += f.x + f.y + f.z + f.w;
    s2 += f.x*f.x + f.y*f.y + f.z*f.z + f.w*f.w;
  }
#pragma unroll
  for (int off = 32; off > 0; off >>= 1) { s1 += __shfl_xor(s1, off); s2 += __shfl_xor(s2, off); }
  const float mu = s1 * (1.f / 768.f);
  const float var = s2 * (1.f / 768.f) - mu * mu;
  const float rs = rsqrtf(var + 1e-6f);
#pragma unroll
  for (int t = 0; t < 3; ++t) {
    int c = (t * 64 + lane) * 4;
    u32 lo = (u32)f2b((v[t*4+0]-mu)*rs*sc[c+0] + bi[c+0]) | ((u32)f2b((v[t*4+1]-mu)*rs*sc[c+1] + bi[c+1]) << 16);
    u32 hi = (u32)f2b((v[t*4+2]-mu)*rs*sc[c+2] + bi[c+2]) | ((u32)f2b((v[t*4+3]-mu)*rs*sc[c+3] + bi[c+3]) << 16);
    yrow[(t*64+lane)*2]   = lo;
    yrow[(t*64+lane)*2+1] = hi;
  }
}

// ---------- 128x128 bf16 MFMA GEMM, A[Mpad][K] @ Bt[N][K]^T, 4 epilogues ----------
template<int EPI>
__global__ __launch_bounds__(256)
void gemm128(const u16* __restrict__ A, const u16* __restrict__ Bt,
             const float* __restrict__ bias, float* __restrict__ outf,
             u16* __restrict__ outh, const float* __restrict__ resid,
             u16* __restrict__ qkvout, int K) {
  __shared__ u16 As[128 * 32];
  __shared__ u16 Bs[128 * 32];
  const int tid = threadIdx.x;
  const int lane = tid & 63, wid = tid >> 6;
  const int wr = wid >> 1, wc = wid & 1;
  const int m0 = blockIdx.y * 128, n0 = blockIdx.x * 128;

  f32x4 acc[4][4] = {};

  const int c1 = wid * 64 + lane;
  const int row1 = c1 >> 2, kp1 = (c1 & 3) * 8;
  const int c2 = c1 + 256;
  const int row2 = c2 >> 2, kp2 = (c2 & 3) * 8;
  const u16* a1 = A + (size_t)(m0 + row1) * K + kp1;
  const u16* a2 = A + (size_t)(m0 + row2) * K + kp2;
  const u16* b1 = Bt + (size_t)(n0 + row1) * K + kp1;
  const u16* b2 = Bt + (size_t)(n0 + row2) * K + kp2;
  u16* lA0 = As + wid * 512;  u16* lA1 = As + wid * 512 + 2048;
  u16* lB0 = Bs + wid * 512;  u16* lB1 = Bs + wid * 512 + 2048;

  const int ar = lane & 15, kk = (lane >> 4) * 8;

  for (int kt = 0; kt < K; kt += 32) {
    __syncthreads();
    gll16(a1 + kt, lA0);
    gll16(a2 + kt, lA1);
    gll16(b1 + kt, lB0);
    gll16(b2 + kt, lB1);
    __syncthreads();
    bf16x8 af[4], bfv[4];
#pragma unroll
    for (int i = 0; i < 4; ++i) {
      af[i]  = *(const bf16x8*)(As + (wr * 64 + i * 16 + ar) * 32 + kk);
      bfv[i] = *(const bf16x8*)(Bs + (wc * 64 + i * 16 + ar) * 32 + kk);
    }
#pragma unroll
    for (int i = 0; i < 4; ++i)
#pragma unroll
      for (int j = 0; j < 4; ++j)
        acc[i][j] = __builtin_amdgcn_mfma_f32_16x16x32_bf16(af[i], bfv[j], acc[i][j], 0, 0, 0);
  }

  const int rbase = m0 + wr * 64 + (lane >> 4) * 4;
  const int cbase = n0 + wc * 64 + (lane & 15);
#pragma unroll
  for (int i = 0; i < 4; ++i) {
#pragma unroll
    for (int j = 0; j < 4; ++j) {
      const int col = cbase + j * 16;
#pragma unroll
      for (int r = 0; r < 4; ++r) {
        const int row = rbase + i * 16 + r;
        float v = acc[i][j][r];
        if constexpr (EPI == 0) {
          if (row < 19600) {
            v += bias[col];
            if (col < 768) v *= 0.125f;  // fold softmax scale into Q (pow2: lossless)
            int s = col / 768, rem = col % 768;
            int head = rem >> 6, d = rem & 63;
            int win = row / 196, l = row % 196;
            qkvout[(size_t)s * 15052800 + ((size_t)(win * 12 + head) * 196 + l) * 64 + d] = f2b(v);
          }
        } else if constexpr (EPI == 1) {
          if (row < 19600) {
            int win = row / 196, l = row % 196;
            int b = win / 25, wh = (win / 5) % 5, ww = win % 5;
            int i2 = l / 14, j2 = l % 14;
            int h = wh * 14 + i2, w = ww * 14 + j2;
            if (h < 64 && w < 64) {
              size_t idx = ((size_t)((b * 64 + h) * 64 + w)) * 768 + col;
              outf[idx] = resid[idx] + v + bias[col];
            }
          }
        } else if constexpr (EPI == 2) {
          float t = v + bias[col];
          float g = 0.5f * t * (1.0f + erff(t * 0.70710678118f));
          outh[(size_t)row * 3072 + col] = f2b(g);
        } else {
          size_t idx = (size_t)row * 768 + col;
          outf[idx] = outf[idx] + v + bias[col];
        }
      }
    }
  }
}

// ---------- rel-pos bias via MFMA: D = Qs @ Rel^T, inverse-gather scatter to BH/BW ----------
// BH[wh][row][ki] = q[row]·relh[li-ki+13]; each D[row][rel] maps to ki = li-rel+13 (unique).
// No LDS; rel B-frags built in registers from f32 tables (x8 un-scale folded, pow2 lossless).
__global__ __launch_bounds__(256)
void relbias_mfma(const u16* __restrict__ qkv, const float* __restrict__ relh,
                  const float* __restrict__ relw, u16* __restrict__ BH,
                  u16* __restrict__ BW) {
  const int tid = threadIdx.x;
  const int lane = tid & 63, w = tid >> 6;
  const int c = lane & 15, g = lane >> 4;
  const int wh = blockIdx.x;
  const u16* qg = qkv + (size_t)wh * 12544;

  // B-frags: col = rel = ct*16+c, k = kh*32 + g*8 .. +8
  bf16x8 hf[2][2], wf[2][2];
#pragma unroll
  for (int ct = 0; ct < 2; ++ct) {
    int rel = ct * 16 + c;
#pragma unroll
    for (int kh = 0; kh < 2; ++kh) {
      union { u16 e[8]; bf16x8 v; } hu, wu;
#pragma unroll
      for (int j = 0; j < 8; ++j) { hu.e[j] = 0; wu.e[j] = 0; }
      if (rel < 27) {
        const float* hp = relh + rel * 64 + kh * 32 + g * 8;
        const float* wp = relw + rel * 64 + kh * 32 + g * 8;
#pragma unroll
        for (int j = 0; j < 8; ++j) { hu.e[j] = f2b(8.f * hp[j]); wu.e[j] = f2b(8.f * wp[j]); }
      }
      hf[ct][kh] = hu.v; wf[ct][kh] = wu.v;
    }
  }

  for (int rt = w; rt < 13; rt += 4) {
    const int rbase = rt * 16;
    bf16x8 qf0 = bzero(), qf1 = bzero();
    {
      int qrow = rbase + c;
      if (qrow < 196) {
        qf0 = *(const bf16x8*)(qg + qrow * 64 + g * 8);
        qf1 = *(const bf16x8*)(qg + qrow * 64 + 32 + g * 8);
      }
    }
    f32x4 aH[2], aW[2];
#pragma unroll
    for (int ct = 0; ct < 2; ++ct) { aH[ct] = (f32x4){0,0,0,0}; aW[ct] = (f32x4){0,0,0,0}; }
#pragma unroll
    for (int ct = 0; ct < 2; ++ct) {
      aH[ct] = __builtin_amdgcn_mfma_f32_16x16x32_bf16(qf0, hf[ct][0], aH[ct], 0, 0, 0);
      aH[ct] = __builtin_amdgcn_mfma_f32_16x16x32_bf16(qf1, hf[ct][1], aH[ct], 0, 0, 0);
      aW[ct] = __builtin_amdgcn_mfma_f32_16x16x32_bf16(qf0, wf[ct][0], aW[ct], 0, 0, 0);
      aW[ct] = __builtin_amdgcn_mfma_f32_16x16x32_bf16(qf1, wf[ct][1], aW[ct], 0, 0, 0);
    }
    // C layout: row = g*4+r, col = rel. Inverse gather: ki = li - rel + 13 in [0,14).
#pragma unroll
    for (int ct = 0; ct < 2; ++ct) {
      int rel = ct * 16 + c;
      if (rel < 27) {
#pragma unroll
        for (int r = 0; r < 4; ++r) {
          int row = rbase + g * 4 + r;
          if (row < 196) {
            int li = row / 14, lj = row - li * 14;
            int ki = li - rel + 13;
            if (ki >= 0 && ki < 14)
              BH[(size_t)wh * 2744 + row * 14 + ki] = f2b(aH[ct][r]);
            int kj = lj - rel + 13;
            if (kj >= 0 && kj < 14)
              BW[(size_t)wh * 2744 + row * 14 + kj] = f2b(aW[ct][r]);
          }
        }
      }
    }
  }
}

// ---------- MFMA attention: block = (window, head), 4 waves, 80KB LDS ----------
// (R3-verified version: Bst staging from global BH/BW; u16-typed LDS throughout.)
// All LDS XOR-swizzled: byte = (row*stride + 2k) ^ ((row&7)<<4)  [16B-granule perm]
__global__ __launch_bounds__(256)
void attn_mfma(const u16* __restrict__ qkv, const u16* __restrict__ BHg,
               const u16* __restrict__ BWg, u16* __restrict__ obuf) {
  __shared__ u16 Ks[196 * 64];        // 25,088 B  (B-frag source for S)
  __shared__ u16 Vt[64 * 208];        // 26,624 B  (V^T, cols>=196 zero)
  __shared__ u16 Pst[4][16 * 208];    // 26,624 B  (per-wave P strip)
  __shared__ u16 Bst[4][448];         // 3,584 B   (per-wave BH/BW strip, u32-staged)

  const int tid = threadIdx.x;
  const int lane = tid & 63, w = tid >> 6;
  const int c = lane & 15, g = lane >> 4;
  const int wh = blockIdx.x;
  const int win = wh / 12, head = wh % 12;
  const u16* qg = qkv + (size_t)wh * 12544;
  const u16* kg = qg + 15052800;
  const u16* vg = qg + 30105600;

  // phase 0: zero Vt (pad cols must be 0)
  for (int i = tid; i < 1664; i += 256) ((uint4*)Vt)[i] = make_uint4(0, 0, 0, 0);
  __syncthreads();
  // phase 1: stage K (swizzled 16B chunks) + V transposed (swizzled u16 scatter)
  for (int idx = tid; idx < 1568; idx += 256) {
    int row = idx >> 3, ch = idx & 7;
    uint4 d = *(const uint4*)(kg + row * 64 + ch * 8);
    *(uint4*)((char*)Ks + (((u32)row * 128 + ch * 16) ^ ((row & 7) << 4))) = d;
  }
  for (int idx = tid; idx < 1568; idx += 256) {
    int k = idx >> 3, c0 = (idx & 7) * 8;
    uint4 d = *(const uint4*)(vg + k * 64 + c0);
    u16 e[8];
    e[0] = d.x & 0xFFFF; e[1] = d.x >> 16; e[2] = d.y & 0xFFFF; e[3] = d.y >> 16;
    e[4] = d.z & 0xFFFF; e[5] = d.z >> 16; e[6] = d.w & 0xFFFF; e[7] = d.w >> 16;
#pragma unroll
    for (int j = 0; j < 8; ++j) {
      int col = c0 + j;
      u32 byte = ((u32)col * 416 + 2 * k) ^ ((col & 7) << 4);
      *(u16*)((char*)Vt + byte) = e[j];
    }
  }
  __syncthreads();

  // row-tile loop: wave w owns tiles w, w+4, w+8 (+12 for w==0)
  for (int rt = w; rt < 13; rt += 4) {
    const int rbase = rt * 16;

    // Q A-frags direct from global (guarded)
    bf16x8 qf0 = bzero(), qf1 = bzero();
    {
      int qrow = rbase + c;
      if (qrow < 196) {
        qf0 = *(const bf16x8*)(qg + qrow * 64 + g * 8);
        qf1 = *(const bf16x8*)(qg + qrow * 64 + 32 + g * 8);
      }
    }
    // stage bias strip (16 rows x 14 of BH and BW) as u32s
#pragma unroll
    for (int t = 0; t < 4; ++t) {
      int idx = lane + t * 64;
      if (idx < 224) {
        const u32* src = (const u32*)((idx < 112) ? BHg : BWg);
        int off = (idx < 112) ? idx : idx - 112;
        ((u32*)Bst[w])[idx] = src[(size_t)(wh * 196 + rbase) * 7 + off];
      }
    }

    // ---- S = Qs @ K^T ----
    f32x4 acc[13];
#pragma unroll
    for (int ct = 0; ct < 13; ++ct) acc[ct] = (f32x4){0.f, 0.f, 0.f, 0.f};
#pragma unroll
    for (int ct = 0; ct < 13; ++ct) {
      int kcol = ct * 16 + c;
      bf16x8 kf0 = bzero(), kf1 = bzero();
      if (kcol < 196) {
        u32 b0 = ((u32)kcol * 128 + g * 16) ^ ((kcol & 7) << 4);
        u32 b1 = ((u32)kcol * 128 + 64 + g * 16) ^ ((kcol & 7) << 4);
        kf0 = *(const bf16x8*)((char*)Ks + b0);
        kf1 = *(const bf16x8*)((char*)Ks + b1);
      }
      acc[ct] = __builtin_amdgcn_mfma_f32_16x16x32_bf16(qf0, kf0, acc[ct], 0, 0, 0);
      acc[ct] = __builtin_amdgcn_mfma_f32_16x16x32_bf16(qf1, kf1, acc[ct], 0, 0, 0);
    }

    // ---- bias add + mask + softmax (C-frag layout: row=g*4+r, col=ct*16+c) ----
    float m0[4] = {-3e38f, -3e38f, -3e38f, -3e38f};
#pragma unroll
    for (int ct = 0; ct < 13; ++ct) {
      int k = ct * 16 + c;
      bool valid = k < 196;
      int ki = valid ? (k / 14) : 0;
      int kj = valid ? (k - ki * 14) : 0;
#pragma unroll
      for (int r = 0; r < 4; ++r) {
        int rr = g * 4 + r;
        float v;
        if (valid) v = acc[ct][r] + b2f(Bst[w][rr * 14 + ki]) + b2f(Bst[w][224 + rr * 14 + kj]);
        else v = -3e38f;
        acc[ct][r] = v;
        m0[r] = fmaxf(m0[r], v);
      }
    }
#pragma unroll
    for (int r = 0; r < 4; ++r) {
      m0[r] = fmaxf(m0[r], __shfl_xor(m0[r], 1));
      m0[r] = fmaxf(m0[r], __shfl_xor(m0[r], 2));
      m0[r] = fmaxf(m0[r], __shfl_xor(m0[r], 4));
      m0[r] = fmaxf(m0[r], __shfl_xor(m0[r], 8));
    }
    float sum[4] = {0.f, 0.f, 0.f, 0.f};
#pragma unroll
    for (int ct = 0; ct < 13; ++ct)
#pragma unroll
      for (int r = 0; r < 4; ++r) {
        float p = __expf(acc[ct][r] - m0[r]);
        acc[ct][r] = p;
        sum[r] += p;
      }
#pragma unroll
    for (int r = 0; r < 4; ++r) {
      sum[r] += __shfl_xor(sum[r], 1);
      sum[r] += __shfl_xor(sum[r], 2);
      sum[r] += __shfl_xor(sum[r], 4);
      sum[r] += __shfl_xor(sum[r], 8);
      sum[r] = 1.f / sum[r];
    }
    // write P strip (bf16, swizzled)
#pragma unroll
    for (int ct = 0; ct < 13; ++ct) {
      int k2 = 2 * (ct * 16 + c);
#pragma unroll
      for (int r = 0; r < 4; ++r) {
        int rr = g * 4 + r;
        u32 byte = ((u32)rr * 416 + k2) ^ ((rr & 7) << 4);
        *(u16*)((char*)Pst[w] + byte) = f2b(acc[ct][r] * sum[r]);
      }
    }

    // ---- O = P @ V (A = P strip, B = Vt rows) ----
    f32x4 o[4];
#pragma unroll
    for (int nt = 0; nt < 4; ++nt) o[nt] = (f32x4){0.f, 0.f, 0.f, 0.f};
#pragma unroll
    for (int ks = 0; ks < 7; ++ks) {
      int slice = ks * 32 + g * 8;
      bf16x8 pa = bzero();
      if (slice < 208) {
        u32 byte = ((u32)c * 416 + 2 * slice) ^ ((c & 7) << 4);
        pa = *(const bf16x8*)((char*)Pst[w] + byte);
      }
#pragma unroll
      for (int nt = 0; nt < 4; ++nt) {
        bf16x8 vb = bzero();
        if (slice < 208) {
          int n = nt * 16 + c;
          u32 byte = ((u32)n * 416 + 2 * slice) ^ ((n & 7) << 4);
          vb = *(const bf16x8*)((char*)Vt + byte);
        }
        o[nt] = __builtin_amdgcn_mfma_f32_16x16x32_bf16(pa, vb, o[nt], 0, 0, 0);
      }
    }
    // write O rows (C layout: row=g*4+r -> q, col=nt*16+c -> d)
#pragma unroll
    for (int nt = 0; nt < 4; ++nt) {
#pragma unroll
      for (int r = 0; r < 4; ++r) {
        int q = rbase + g * 4 + r;
        if (q < 196)
          obuf[(size_t)(win * 196 + q) * 768 + head * 64 + nt * 16 + c] = f2b(o[nt][r]);
      }
    }
  }
}

extern "C" void kernel_launch(void* const* d_in, const int* in_sizes, int n_in,
                              void* d_out, int out_size, void* d_ws, size_t ws_size,
                              hipStream_t stream) {
  const float* x      = (const float*)d_in[0];
  const float* n1s    = (const float*)d_in[1];
  const float* n1b    = (const float*)d_in[2];
  const float* qkv_w  = (const float*)d_in[3];
  const float* qkv_b  = (const float*)d_in[4];
  const float* rel_h  = (const float*)d_in[5];
  const float* rel_w  = (const float*)d_in[6];
  const float* proj_w = (const float*)d_in[7];
  const float* proj_b = (const float*)d_in[8];
  const float* n2s    = (const float*)d_in[9];
  const float* n2b    = (const float*)d_in[10];
  const float* fc1_w  = (const float*)d_in[11];
  const float* fc1_b  = (const float*)d_in[12];
  const float* fc2_w  = (const float*)d_in[13];
  const float* fc2_b  = (const float*)d_in[14];
  float* out = (float*)d_out;

  char* ws = (char*)d_ws;
  u16* qkv_wt = (u16*)(ws + 0);            // [2304][768]
  u16* proj_wt = (u16*)(ws + 3538944);     // [768][768]
  u16* fc1_wt = (u16*)(ws + 4718592);      // [3072][768]
  u16* fc2_wt = (u16*)(ws + 9437184);      // [768][3072]
  u16* ywin   = (u16*)(ws + 14155776);     // [19712][768]; later obuf; later m1 head
  u16* qkvbuf = (u16*)(ws + 44433408);     // [3][1200][196][64]
  u16* m1     = ywin;                      // [16384][3072] spans ywin+qkvbuf
  u16* h2     = (u16*)(ws + 114819072);    // [16384][768]
  u16* BH     = (u16*)(ws + 139984896);    // [1200][196][14] bf16
  u16* BW     = (u16*)(ws + 146570496);    // [1200][196][14] bf16
  if (ws_size < 153160192) return;         // diagnosable: leaves d_out poisoned

  castT<<<dim3(72, 24), 256, 0, stream>>>(qkv_w, qkv_wt, 768, 2304);
  castT<<<dim3(24, 24), 256, 0, stream>>>(proj_w, proj_wt, 768, 768);
  castT<<<dim3(96, 24), 256, 0, stream>>>(fc1_w, fc1_wt, 768, 3072);
  castT<<<dim3(24, 96), 256, 0, stream>>>(fc2_w, fc2_wt, 3072, 768);

  ln1win_kernel<<<19712, 64, 0, stream>>>(x, n1s, n1b, ywin);

  gemm128<0><<<dim3(18, 154), 256, 0, stream>>>(ywin, qkv_wt, qkv_b, nullptr, nullptr, nullptr, qkvbuf, 768);

  relbias_mfma<<<1200, 256, 0, stream>>>(qkvbuf, rel_h, rel_w, BH, BW);

  attn_mfma<<<1200, 256, 0, stream>>>(qkvbuf, BH, BW, ywin /* obuf */);

  gemm128<1><<<dim3(6, 154), 256, 0, stream>>>(ywin, proj_wt, proj_b, out, nullptr, x, nullptr, 768);

  ln2_kernel<<<16384, 64, 0, stream>>>(out, n2s, n2b, h2);

  gemm128<2><<<dim3(24, 128), 256, 0, stream>>>(h2, fc1_wt, fc1_b, nullptr, m1, nullptr, nullptr, 768);

  gemm128<3><<<dim3(6, 128), 256, 0, stream>>>(m1, fc2_wt, fc2_b, out, nullptr, nullptr, nullptr, 3072);
}